// Round 3
// baseline (1331.441 us; speedup 1.0000x reference)
//
#include <hip/hip_runtime.h>

typedef unsigned short u16;
typedef __attribute__((ext_vector_type(4))) float f32x4;
typedef __attribute__((ext_vector_type(4))) unsigned short u16x4;
typedef __attribute__((ext_vector_type(8))) short s16x8;

#define DEV __device__ __forceinline__

DEV float bf2f(u16 h) { union { unsigned u; float f; } x; x.u = ((unsigned)h) << 16; return x.f; }
DEV u16 f2bf(float f) {
  union { float f; unsigned u; } x; x.f = f;
  unsigned r = x.u + 0x7fffu + ((x.u >> 16) & 1u);
  return (u16)(r >> 16);
}

DEV void async_copy16(u16* lds_dst, const u16* g_src) {
  __builtin_amdgcn_global_load_lds(
      (const __attribute__((address_space(1))) unsigned int*)g_src,
      (__attribute__((address_space(3))) unsigned int*)lds_dst, 16, 0, 0);
}

// ---------------------------------------------------------------------------
// f32 -> bf16 conversion (vectorized)
__global__ __launch_bounds__(256) void cvt_f32_bf16(const float* __restrict__ in,
                                                    u16* __restrict__ out, int n4) {
  int i = blockIdx.x * 256 + threadIdx.x;
  if (i < n4) {
    f32x4 v = ((const f32x4*)in)[i];
    u16x4 o;
    o.x = f2bf(v.x); o.y = f2bf(v.y); o.z = f2bf(v.z); o.w = f2bf(v.w);
    ((u16x4*)out)[i] = o;
  }
}

// ---------------------------------------------------------------------------
// LayerNorm over D=1024, one block (256 thr) per token.
// Writes bf16 always; optionally also writes f32. `in`/`outF` may alias
// (in-place rewrite): each thread reads its own 4 elements before writing the
// same 4 — no __restrict__ on these two on purpose.
__global__ __launch_bounds__(256) void ln_kernel(const float* in,
                                                 const float* __restrict__ g,
                                                 const float* __restrict__ be,
                                                 u16* __restrict__ out,
                                                 float* outF) {
  const int t = blockIdx.x;
  const int tid = threadIdx.x;
  __shared__ float red[16];
  f32x4 v = ((const f32x4*)(in + (size_t)t * 1024))[tid];
  float s  = v.x + v.y + v.z + v.w;
  float s2 = v.x * v.x + v.y * v.y + v.z * v.z + v.w * v.w;
#pragma unroll
  for (int o = 1; o < 64; o <<= 1) { s += __shfl_xor(s, o); s2 += __shfl_xor(s2, o); }
  const int w = tid >> 6, lane = tid & 63;
  if (lane == 0) { red[w] = s; red[8 + w] = s2; }
  __syncthreads();
  s  = red[0] + red[1] + red[2] + red[3];
  s2 = red[8] + red[9] + red[10] + red[11];
  const float mean = s * (1.f / 1024.f);
  const float rst  = rsqrtf(s2 * (1.f / 1024.f) - mean * mean + 1e-5f);
  f32x4 gv  = ((const f32x4*)g)[tid];
  f32x4 bev = ((const f32x4*)be)[tid];
  f32x4 y;
  y.x = (v.x - mean) * rst * gv.x + bev.x;
  y.y = (v.y - mean) * rst * gv.y + bev.y;
  y.z = (v.z - mean) * rst * gv.z + bev.z;
  y.w = (v.w - mean) * rst * gv.w + bev.w;
  u16x4 o;
  o.x = f2bf(y.x); o.y = f2bf(y.y); o.z = f2bf(y.z); o.w = f2bf(y.w);
  ((u16x4*)out)[(size_t)t * 256 + tid] = o;
  if (outF) ((f32x4*)(outF + (size_t)t * 1024))[tid] = y;
}

// ---------------------------------------------------------------------------
// B projection: in-kernel f32 LN (exact path for last_h), gated B -> bg_tr[(b*16+h)][l]
__global__ __launch_bounds__(256) void bproj_kernel(
    const float* __restrict__ bv, const float* __restrict__ g1, const float* __restrict__ be1,
    const float* __restrict__ Wb, const float* __restrict__ bb,
    const float* __restrict__ Wbg, const float* __restrict__ bbg,
    float* __restrict__ bg_tr) {
  const int t = blockIdx.x;
  const int tid = threadIdx.x;
  __shared__ float xs[1024];
  __shared__ float red[16];
  f32x4 v = ((const f32x4*)(bv + (size_t)t * 1024))[tid];
  float s  = v.x + v.y + v.z + v.w;
  float s2 = v.x * v.x + v.y * v.y + v.z * v.z + v.w * v.w;
#pragma unroll
  for (int o = 1; o < 64; o <<= 1) { s += __shfl_xor(s, o); s2 += __shfl_xor(s2, o); }
  const int w = tid >> 6, lane = tid & 63;
  if (lane == 0) { red[w] = s; red[8 + w] = s2; }
  __syncthreads();
  s  = red[0] + red[1] + red[2] + red[3];
  s2 = red[8] + red[9] + red[10] + red[11];
  const float mean = s * (1.f / 1024.f);
  const float rst  = rsqrtf(s2 * (1.f / 1024.f) - mean * mean + 1e-5f);
  f32x4 gv  = ((const f32x4*)g1)[tid];
  f32x4 bev = ((const f32x4*)be1)[tid];
  f32x4 y;
  y.x = (v.x - mean) * rst * gv.x + bev.x;
  y.y = (v.y - mean) * rst * gv.y + bev.y;
  y.z = (v.z - mean) * rst * gv.z + bev.z;
  y.w = (v.w - mean) * rst * gv.w + bev.w;
  ((f32x4*)xs)[tid] = y;
  __syncthreads();
  const int h = tid >> 4, c = tid & 15;
  const float* wb  = Wb + h * 1024;
  const float* wbg = Wbg + h * 1024;
  float p = 0.f, pg = 0.f;
  for (int i = c; i < 1024; i += 16) {
    float xv = xs[i];
    p += xv * wb[i];
    pg += xv * wbg[i];
  }
#pragma unroll
  for (int o = 1; o < 16; o <<= 1) { p += __shfl_xor(p, o); pg += __shfl_xor(pg, o); }
  if (c == 0) {
    float gate = 1.f / (1.f + expf(-(pg + bbg[h])));
    bg_tr[(((t >> 10) * 16 + h)) * 1024 + (t & 1023)] = (p + bb[h]) * gate;
  }
}

// ---------------------------------------------------------------------------
// Selective scan: 64 threads = (b,h) pairs. Writes hs[t][16] and last_h.
__global__ void scan_kernel(const float* __restrict__ bg_tr, const float* __restrict__ A,
                            const float* __restrict__ h0, float* __restrict__ hs,
                            float* __restrict__ lasth) {
  const int i = threadIdx.x;  // 0..63
  const int b = i >> 4, h = i & 15;
  const float delta = expf(A[h]);
  float hv = h0[b * 16 + h];
  const float* src = bg_tr + (size_t)i * 1024;
  for (int l = 0; l < 1024; l += 4) {
    f32x4 bx = *(const f32x4*)(src + l);
    hv = delta * hv + bx.x; hs[((size_t)(b << 10) + l + 0) * 16 + h] = hv;
    hv = delta * hv + bx.y; hs[((size_t)(b << 10) + l + 1) * 16 + h] = hv;
    hv = delta * hv + bx.z; hs[((size_t)(b << 10) + l + 2) * 16 + h] = hv;
    hv = delta * hv + bx.w; hs[((size_t)(b << 10) + l + 3) * 16 + h] = hv;
  }
  lasth[b * 16 + h] = hv;
}

// ---------------------------------------------------------------------------
// Fused: u[t,o] = bv[t,o] + (x@Wd.T + bd)[t,o]
//                 + sum_h hs[t,h] * ((x@Wc.T+bc)*sigmoid(x@Wcg.T+bcg))[t,h,o]
// 256 blocks: lin&7 -> o-tile (XCD affinity for weight reuse), lin>>3 -> m-tile.
// 128x128 tile, BK=32, 4 waves x 64x64, double-buffered LDS (2-phase), 17 h-passes.
__global__ __launch_bounds__(256, 1) void fused_cgemm(
    const u16* __restrict__ xbf, const u16* __restrict__ wc, const u16* __restrict__ wcg,
    const u16* __restrict__ wd, const float* __restrict__ bc, const float* __restrict__ bcg,
    const float* __restrict__ bd, const float* __restrict__ hs, const float* __restrict__ bv,
    float* __restrict__ u) {
  __shared__ u16 lds_a[2][128 * 32];
  __shared__ u16 lds_b[2][128 * 32];
  __shared__ u16 lds_g[2][128 * 32];
  __shared__ float hs_lds[128 * 16];

  const int tid = threadIdx.x;
  const int lane = tid & 63;
  const int w = tid >> 6;
  const int wm = w & 1, wn = w >> 1;
  const int row16 = lane & 15, kg = lane >> 4;

  const int lin = blockIdx.x;
  const int obase = (lin & 7) * 128;
  const int rowA = (lin >> 3) * 128;

  // preload hs tile (128 tokens x 16 h) into LDS
  {
    f32x4 h0v = *(const f32x4*)(hs + (size_t)rowA * 16 + tid * 8);
    f32x4 h1v = *(const f32x4*)(hs + (size_t)rowA * 16 + tid * 8 + 4);
    *(f32x4*)(hs_lds + tid * 8) = h0v;
    *(f32x4*)(hs_lds + tid * 8 + 4) = h1v;
  }

  f32x4 accu[4][4] = {};
  f32x4 acc[4][4] = {};
  f32x4 accg[4][4] = {};

  auto stage = [&](int buf, int step) {
    const int h = step >> 5;
    const int k = (step & 31) * 32;
#pragma unroll
    for (int s = 0; s < 2; ++s) {
      const int slot = s * 256 + tid;
      const int r = slot >> 2;
      const int c = (slot & 3) << 3;
      async_copy16(&lds_a[buf][slot * 8], xbf + (size_t)(rowA + r) * 1024 + k + c);
      if (h < 16) {
        const size_t brow = (size_t)(h * 1024 + obase + r) * 1024 + k + c;
        async_copy16(&lds_b[buf][slot * 8], wc + brow);
        async_copy16(&lds_g[buf][slot * 8], wcg + brow);
      } else {
        async_copy16(&lds_b[buf][slot * 8], wd + (size_t)(obase + r) * 1024 + k + c);
      }
    }
  };

  stage(0, 0);
  __syncthreads();

  for (int step = 0; step < 544; ++step) {
    const int buf = step & 1;
    const int h = step >> 5;
    if (step + 1 < 544) stage(buf ^ 1, step + 1);

    s16x8 af[4], bfr[4], gfr[4];
#pragma unroll
    for (int i = 0; i < 4; ++i)
      af[i] = *(const s16x8*)&lds_a[buf][(wm * 64 + i * 16 + row16) * 32 + kg * 8];
#pragma unroll
    for (int i = 0; i < 4; ++i)
      bfr[i] = *(const s16x8*)&lds_b[buf][(wn * 64 + i * 16 + row16) * 32 + kg * 8];
    if (h < 16) {
#pragma unroll
      for (int i = 0; i < 4; ++i)
        gfr[i] = *(const s16x8*)&lds_g[buf][(wn * 64 + i * 16 + row16) * 32 + kg * 8];
    }

#pragma unroll
    for (int mi = 0; mi < 4; ++mi)
#pragma unroll
      for (int ni = 0; ni < 4; ++ni)
        acc[mi][ni] = __builtin_amdgcn_mfma_f32_16x16x32_bf16(af[mi], bfr[ni], acc[mi][ni], 0, 0, 0);
    if (h < 16) {
#pragma unroll
      for (int mi = 0; mi < 4; ++mi)
#pragma unroll
        for (int ni = 0; ni < 4; ++ni)
          accg[mi][ni] =
              __builtin_amdgcn_mfma_f32_16x16x32_bf16(af[mi], gfr[ni], accg[mi][ni], 0, 0, 0);
    }

    if ((step & 31) == 31) {  // end of one h-pass: fold into accu
      if (h < 16) {
#pragma unroll
        for (int ni = 0; ni < 4; ++ni) {
          const int ocol = obase + wn * 64 + ni * 16 + row16;
          const float b0 = bc[h * 1024 + ocol];
          const float b1 = bcg[h * 1024 + ocol];
#pragma unroll
          for (int mi = 0; mi < 4; ++mi) {
#pragma unroll
            for (int j = 0; j < 4; ++j) {
              const int lrow = wm * 64 + mi * 16 + kg * 4 + j;
              const float hv = hs_lds[lrow * 16 + h];
              const float vv = acc[mi][ni][j] + b0;
              const float vg = accg[mi][ni][j] + b1;
              accu[mi][ni][j] += hv * vv / (1.f + expf(-vg));
              acc[mi][ni][j] = 0.f;
              accg[mi][ni][j] = 0.f;
            }
          }
        }
      } else {  // Dout pass
#pragma unroll
        for (int ni = 0; ni < 4; ++ni) {
          const int ocol = obase + wn * 64 + ni * 16 + row16;
          const float b0 = bd[ocol];
#pragma unroll
          for (int mi = 0; mi < 4; ++mi)
#pragma unroll
            for (int j = 0; j < 4; ++j)
              accu[mi][ni][j] += acc[mi][ni][j] + b0;
        }
      }
    }
    __syncthreads();
  }

  // write u = accu + bv
#pragma unroll
  for (int mi = 0; mi < 4; ++mi)
#pragma unroll
    for (int ni = 0; ni < 4; ++ni) {
      const int ocol = obase + wn * 64 + ni * 16 + row16;
#pragma unroll
      for (int j = 0; j < 4; ++j) {
        const int grow = rowA + wm * 64 + mi * 16 + kg * 4 + j;
        const size_t idx = (size_t)grow * 1024 + ocol;
        u[idx] = accu[mi][ni][j] + bv[idx];
      }
    }
}

// ---------------------------------------------------------------------------
// Plain GEMM: C[m,n] = sum_k A[m,k]*B0[n,k], wave tile 64x64, WM x WN waves.
// EPI: 2 = gelu(acc+bias) -> bf16 out; 3 = acc+bias+residF -> f32 out
// outF/residF may alias (same element, same thread) -> no __restrict__ on them.
template <int WM, int WN, int EPI>
__global__ __launch_bounds__(WM * WN * 64, 2) void gemm_t(
    const u16* __restrict__ A, const u16* __restrict__ B0, const float* __restrict__ bias0,
    float* outF, u16* __restrict__ outB, const float* residF,
    int N, int K) {
  constexpr int BM = WM * 64, BN = WN * 64, BK = 32, T = WM * WN * 64;
  __shared__ u16 lds_a[BM * BK];
  __shared__ u16 lds_b[BN * BK];
  const int tid = threadIdx.x;
  const int lane = tid & 63;
  const int w = tid >> 6;
  const int wm = w % WM, wn = w / WM;
  const int row16 = lane & 15, kg = lane >> 4;
  const size_t rowA = (size_t)blockIdx.x * BM;
  const size_t rowB = (size_t)blockIdx.y * BN;
  f32x4 acc[4][4] = {};

  for (int k0 = 0; k0 < K; k0 += BK) {
#pragma unroll
    for (int s = 0; s < BM * 4 / T; ++s) {
      const int slot = s * T + tid;
      async_copy16(&lds_a[slot * 8], A + (rowA + (slot >> 2)) * K + k0 + ((slot & 3) << 3));
    }
#pragma unroll
    for (int s = 0; s < BN * 4 / T; ++s) {
      const int slot = s * T + tid;
      async_copy16(&lds_b[slot * 8], B0 + (rowB + (slot >> 2)) * K + k0 + ((slot & 3) << 3));
    }
    __syncthreads();

    s16x8 af[4], bfr[4];
#pragma unroll
    for (int i = 0; i < 4; ++i)
      af[i] = *(const s16x8*)&lds_a[(wm * 64 + i * 16 + row16) * BK + kg * 8];
#pragma unroll
    for (int i = 0; i < 4; ++i)
      bfr[i] = *(const s16x8*)&lds_b[(wn * 64 + i * 16 + row16) * BK + kg * 8];
#pragma unroll
    for (int mi = 0; mi < 4; ++mi)
#pragma unroll
      for (int ni = 0; ni < 4; ++ni)
        acc[mi][ni] = __builtin_amdgcn_mfma_f32_16x16x32_bf16(af[mi], bfr[ni], acc[mi][ni], 0, 0, 0);
    __syncthreads();
  }

  const int mbase = (int)rowA + wm * 64;
  const int nbase = (int)rowB + wn * 64;
#pragma unroll
  for (int mi = 0; mi < 4; ++mi) {
#pragma unroll
    for (int ni = 0; ni < 4; ++ni) {
      const int col = nbase + ni * 16 + row16;
      const float b0 = bias0[col];
#pragma unroll
      for (int j = 0; j < 4; ++j) {
        const int rrow = mbase + mi * 16 + kg * 4 + j;
        const size_t idx = (size_t)rrow * N + col;
        const float v = acc[mi][ni][j] + b0;
        if constexpr (EPI == 2) {
          outB[idx] = f2bf(0.5f * v * (1.f + erff(v * 0.70710678118654752f)));
        } else {
          outF[idx] = v + residF[idx];
        }
      }
    }
  }
}

// ---------------------------------------------------------------------------
extern "C" void kernel_launch(void* const* d_in, const int* in_sizes, int n_in,
                              void* d_out, int out_size, void* d_ws, size_t ws_size,
                              hipStream_t stream) {
  const float* bv   = (const float*)d_in[0];
  const float* h0   = (const float*)d_in[1];
  const float* Aarr = (const float*)d_in[2];
  const float* Wb   = (const float*)d_in[3];
  const float* bb   = (const float*)d_in[4];
  const float* Wc   = (const float*)d_in[5];
  const float* bc   = (const float*)d_in[6];
  const float* Wd   = (const float*)d_in[7];
  const float* bd   = (const float*)d_in[8];
  const float* Wbg  = (const float*)d_in[9];
  const float* bbg  = (const float*)d_in[10];
  const float* Wcg  = (const float*)d_in[11];
  const float* bcg  = (const float*)d_in[12];
  const float* W1   = (const float*)d_in[13];
  const float* b1   = (const float*)d_in[14];
  const float* W2   = (const float*)d_in[15];
  const float* b2   = (const float*)d_in[16];
  const float* g1   = (const float*)d_in[17];
  const float* be1  = (const float*)d_in[18];
  const float* g2   = (const float*)d_in[19];
  const float* be2  = (const float*)d_in[20];

  float* out = (float*)d_out;
  float* out_lasth = out + (size_t)4096 * 1024;
  float* u_buf = out;  // u / y2-f32 live in d_out until FFN2 overwrites (same-thread r->w)

  char* p = (char*)d_ws;
  auto take = [&](size_t bytes) -> char* {
    char* r = p;
    p += (bytes + 255) & ~(size_t)255;
    return r;
  };
  u16* wc_bf   = (u16*)take((size_t)16384 * 1024 * 2);  // 32 MB
  u16* wcg_bf  = (u16*)take((size_t)16384 * 1024 * 2);  // 32 MB
  u16* wd_bf   = (u16*)take((size_t)1024 * 1024 * 2);   //  2 MB
  u16* w1_bf   = (u16*)take((size_t)4096 * 1024 * 2);   //  8 MB
  u16* w2_bf   = (u16*)take((size_t)1024 * 4096 * 2);   //  8 MB
  u16* x_bf    = (u16*)take((size_t)4096 * 1024 * 2);   //  8 MB
  float* bg_tr = (float*)take((size_t)64 * 1024 * 4);   // .25 MB
  float* hs    = (float*)take((size_t)4096 * 16 * 4);   // .25 MB
  const size_t need = (size_t)(p - (char*)d_ws);        // ~90.5 MB
  if (ws_size < need) return;  // clean absmax=max|ref| failure signals "ws too small"

  // buffers only live after fused_cgemm completes -> alias onto dead weight regions
  u16* f1_bf = wc_bf;   // 32 MB needed, 32 MB available
  u16* y2_bf = wcg_bf;  //  8 MB needed, 32 MB available

  // 1. weight conversions (every call; ws is re-poisoned between calls)
  cvt_f32_bf16<<<16384, 256, 0, stream>>>(Wc, wc_bf, 16384 * 1024 / 4);
  cvt_f32_bf16<<<16384, 256, 0, stream>>>(Wcg, wcg_bf, 16384 * 1024 / 4);
  cvt_f32_bf16<<<1024, 256, 0, stream>>>(Wd, wd_bf, 1024 * 1024 / 4);
  cvt_f32_bf16<<<4096, 256, 0, stream>>>(W1, w1_bf, 4096 * 1024 / 4);
  cvt_f32_bf16<<<4096, 256, 0, stream>>>(W2, w2_bf, 1024 * 4096 / 4);

  // 2. LN1 -> x_bf16
  ln_kernel<<<4096, 256, 0, stream>>>(bv, g1, be1, x_bf, nullptr);

  // 3. gated B projection (own f32 LN, exact) -> bg_tr[(b*16+h)][l]
  bproj_kernel<<<4096, 256, 0, stream>>>(bv, g1, be1, Wb, bb, Wbg, bbg, bg_tr);

  // 4. scan -> hs[t][16], last_h -> d_out tail
  scan_kernel<<<1, 64, 0, stream>>>(bg_tr, Aarr, h0, hs, out_lasth);

  // 5. fused gated-C GEMM + hs contraction + Dout + bv residual -> u_buf (f32, in d_out)
  fused_cgemm<<<256, 256, 0, stream>>>(x_bf, wc_bf, wcg_bf, wd_bf, bc, bcg, bd, hs, bv, u_buf);

  // 6. LN2 -> y2_bf16 (+ f32 y2 in-place into u_buf for the final residual)
  ln_kernel<<<4096, 256, 0, stream>>>(u_buf, g2, be2, y2_bf, u_buf);

  // 7. FFN1 with exact-erf GELU -> f1_bf (4096 x 4096)
  gemm_t<2, 2, 2><<<dim3(32, 32), 256, 0, stream>>>(y2_bf, w1_bf, b1, nullptr, f1_bf, nullptr,
                                                    4096, 1024);

  // 8. FFN2 + bias + residual(y2 f32) -> d_out f32 (4096 x 1024)
  gemm_t<1, 2, 3><<<dim3(64, 8), 128, 0, stream>>>(f1_bf, w2_bf, b2, out, nullptr, u_buf,
                                                   1024, 4096);
}

// Round 4
// 848.714 us; speedup vs baseline: 1.5688x; 1.5688x over previous
//
#include <hip/hip_runtime.h>

typedef unsigned short u16;
typedef __attribute__((ext_vector_type(4))) float f32x4;
typedef __attribute__((ext_vector_type(4))) unsigned short u16x4;
typedef __attribute__((ext_vector_type(8))) short s16x8;

#define DEV __device__ __forceinline__

DEV float bf2f(u16 h) { union { unsigned u; float f; } x; x.u = ((unsigned)h) << 16; return x.f; }
DEV u16 f2bf(float f) {
  union { float f; unsigned u; } x; x.f = f;
  unsigned r = x.u + 0x7fffu + ((x.u >> 16) & 1u);
  return (u16)(r >> 16);
}

DEV void async_copy16(u16* lds_dst, const u16* g_src) {
  __builtin_amdgcn_global_load_lds(
      (const __attribute__((address_space(1))) unsigned int*)g_src,
      (__attribute__((address_space(3))) unsigned int*)lds_dst, 16, 0, 0);
}

// ---------------------------------------------------------------------------
__global__ __launch_bounds__(256) void cvt_f32_bf16(const float* __restrict__ in,
                                                    u16* __restrict__ out, int n4) {
  int i = blockIdx.x * 256 + threadIdx.x;
  if (i < n4) {
    f32x4 v = ((const f32x4*)in)[i];
    u16x4 o;
    o.x = f2bf(v.x); o.y = f2bf(v.y); o.z = f2bf(v.z); o.w = f2bf(v.w);
    ((u16x4*)out)[i] = o;
  }
}

// ---------------------------------------------------------------------------
// LayerNorm over D=1024, one block per token. in/outF may alias (same-thread r->w).
__global__ __launch_bounds__(256) void ln_kernel(const float* in,
                                                 const float* __restrict__ g,
                                                 const float* __restrict__ be,
                                                 u16* __restrict__ out,
                                                 float* outF) {
  const int t = blockIdx.x;
  const int tid = threadIdx.x;
  __shared__ float red[16];
  f32x4 v = ((const f32x4*)(in + (size_t)t * 1024))[tid];
  float s  = v.x + v.y + v.z + v.w;
  float s2 = v.x * v.x + v.y * v.y + v.z * v.z + v.w * v.w;
#pragma unroll
  for (int o = 1; o < 64; o <<= 1) { s += __shfl_xor(s, o); s2 += __shfl_xor(s2, o); }
  const int w = tid >> 6, lane = tid & 63;
  if (lane == 0) { red[w] = s; red[8 + w] = s2; }
  __syncthreads();
  s  = red[0] + red[1] + red[2] + red[3];
  s2 = red[8] + red[9] + red[10] + red[11];
  const float mean = s * (1.f / 1024.f);
  const float rst  = rsqrtf(s2 * (1.f / 1024.f) - mean * mean + 1e-5f);
  f32x4 gv  = ((const f32x4*)g)[tid];
  f32x4 bev = ((const f32x4*)be)[tid];
  f32x4 y;
  y.x = (v.x - mean) * rst * gv.x + bev.x;
  y.y = (v.y - mean) * rst * gv.y + bev.y;
  y.z = (v.z - mean) * rst * gv.z + bev.z;
  y.w = (v.w - mean) * rst * gv.w + bev.w;
  u16x4 o;
  o.x = f2bf(y.x); o.y = f2bf(y.y); o.z = f2bf(y.z); o.w = f2bf(y.w);
  ((u16x4*)out)[(size_t)t * 256 + tid] = o;
  if (outF) ((f32x4*)(outF + (size_t)t * 1024))[tid] = y;
}

// ---------------------------------------------------------------------------
__global__ __launch_bounds__(256) void bproj_kernel(
    const float* __restrict__ bv, const float* __restrict__ g1, const float* __restrict__ be1,
    const float* __restrict__ Wb, const float* __restrict__ bb,
    const float* __restrict__ Wbg, const float* __restrict__ bbg,
    float* __restrict__ bg_tr) {
  const int t = blockIdx.x;
  const int tid = threadIdx.x;
  __shared__ float xs[1024];
  __shared__ float red[16];
  f32x4 v = ((const f32x4*)(bv + (size_t)t * 1024))[tid];
  float s  = v.x + v.y + v.z + v.w;
  float s2 = v.x * v.x + v.y * v.y + v.z * v.z + v.w * v.w;
#pragma unroll
  for (int o = 1; o < 64; o <<= 1) { s += __shfl_xor(s, o); s2 += __shfl_xor(s2, o); }
  const int w = tid >> 6, lane = tid & 63;
  if (lane == 0) { red[w] = s; red[8 + w] = s2; }
  __syncthreads();
  s  = red[0] + red[1] + red[2] + red[3];
  s2 = red[8] + red[9] + red[10] + red[11];
  const float mean = s * (1.f / 1024.f);
  const float rst  = rsqrtf(s2 * (1.f / 1024.f) - mean * mean + 1e-5f);
  f32x4 gv  = ((const f32x4*)g1)[tid];
  f32x4 bev = ((const f32x4*)be1)[tid];
  f32x4 y;
  y.x = (v.x - mean) * rst * gv.x + bev.x;
  y.y = (v.y - mean) * rst * gv.y + bev.y;
  y.z = (v.z - mean) * rst * gv.z + bev.z;
  y.w = (v.w - mean) * rst * gv.w + bev.w;
  ((f32x4*)xs)[tid] = y;
  __syncthreads();
  const int h = tid >> 4, c = tid & 15;
  const float* wb  = Wb + h * 1024;
  const float* wbg = Wbg + h * 1024;
  float p = 0.f, pg = 0.f;
  for (int i = c; i < 1024; i += 16) {
    float xv = xs[i];
    p += xv * wb[i];
    pg += xv * wbg[i];
  }
#pragma unroll
  for (int o = 1; o < 16; o <<= 1) { p += __shfl_xor(p, o); pg += __shfl_xor(pg, o); }
  if (c == 0) {
    float gate = 1.f / (1.f + expf(-(pg + bbg[h])));
    bg_tr[(((t >> 10) * 16 + h)) * 1024 + (t & 1023)] = (p + bb[h]) * gate;
  }
}

// ---------------------------------------------------------------------------
__global__ void scan_kernel(const float* __restrict__ bg_tr, const float* __restrict__ A,
                            const float* __restrict__ h0, float* __restrict__ hs,
                            float* __restrict__ lasth) {
  const int i = threadIdx.x;  // 0..63
  const int b = i >> 4, h = i & 15;
  const float delta = expf(A[h]);
  float hv = h0[b * 16 + h];
  const float* src = bg_tr + (size_t)i * 1024;
  for (int l = 0; l < 1024; l += 4) {
    f32x4 bx = *(const f32x4*)(src + l);
    hv = delta * hv + bx.x; hs[((size_t)(b << 10) + l + 0) * 16 + h] = hv;
    hv = delta * hv + bx.y; hs[((size_t)(b << 10) + l + 1) * 16 + h] = hv;
    hv = delta * hv + bx.z; hs[((size_t)(b << 10) + l + 2) * 16 + h] = hv;
    hv = delta * hv + bx.w; hs[((size_t)(b << 10) + l + 3) * 16 + h] = hv;
  }
  lasth[b * 16 + h] = hv;
}

// ---------------------------------------------------------------------------
// Gated GEMM (unfused fast path): out_bf[m,n] = (A@B0.T+bias0)*sigmoid(A@B1.T+bias1)
// m97 structure: 128x128x32, 4 waves x 64x64, single-buffer, 2 barriers/step.
__global__ __launch_bounds__(256, 2) void gemm_gated(
    const u16* __restrict__ A, const u16* __restrict__ B0, const u16* __restrict__ B1,
    const float* __restrict__ bias0, const float* __restrict__ bias1,
    u16* __restrict__ outB, int N, int K) {
  __shared__ u16 lds_a[128 * 32];
  __shared__ u16 lds_b[128 * 32];
  __shared__ u16 lds_g[128 * 32];
  const int tid = threadIdx.x;
  const int lane = tid & 63;
  const int w = tid >> 6;
  const int wm = w & 1, wn = w >> 1;
  const int row16 = lane & 15, kg = lane >> 4;
  const size_t rowA = (size_t)blockIdx.x * 128;
  const size_t rowB = (size_t)blockIdx.y * 128;
  f32x4 acc[4][4] = {};
  f32x4 accg[4][4] = {};

  for (int k0 = 0; k0 < K; k0 += 32) {
#pragma unroll
    for (int s = 0; s < 2; ++s) {
      const int slot = s * 256 + tid;
      const int r = slot >> 2;
      const int c = (slot & 3) << 3;
      async_copy16(&lds_a[slot * 8], A + (rowA + r) * K + k0 + c);
      async_copy16(&lds_b[slot * 8], B0 + (rowB + r) * K + k0 + c);
      async_copy16(&lds_g[slot * 8], B1 + (rowB + r) * K + k0 + c);
    }
    __syncthreads();
    s16x8 af[4], bfr[4], gfr[4];
#pragma unroll
    for (int i = 0; i < 4; ++i)
      af[i] = *(const s16x8*)&lds_a[(wm * 64 + i * 16 + row16) * 32 + kg * 8];
#pragma unroll
    for (int i = 0; i < 4; ++i) {
      bfr[i] = *(const s16x8*)&lds_b[(wn * 64 + i * 16 + row16) * 32 + kg * 8];
      gfr[i] = *(const s16x8*)&lds_g[(wn * 64 + i * 16 + row16) * 32 + kg * 8];
    }
#pragma unroll
    for (int mi = 0; mi < 4; ++mi)
#pragma unroll
      for (int ni = 0; ni < 4; ++ni) {
        acc[mi][ni] = __builtin_amdgcn_mfma_f32_16x16x32_bf16(af[mi], bfr[ni], acc[mi][ni], 0, 0, 0);
        accg[mi][ni] =
            __builtin_amdgcn_mfma_f32_16x16x32_bf16(af[mi], gfr[ni], accg[mi][ni], 0, 0, 0);
      }
    __syncthreads();
  }

  const int mbase = (int)rowA + wm * 64;
  const int nbase = (int)rowB + wn * 64;
#pragma unroll
  for (int mi = 0; mi < 4; ++mi)
#pragma unroll
    for (int ni = 0; ni < 4; ++ni) {
      const int col = nbase + ni * 16 + row16;
      const float b0 = bias0[col];
      const float b1 = bias1[col];
#pragma unroll
      for (int j = 0; j < 4; ++j) {
        const int rrow = mbase + mi * 16 + kg * 4 + j;
        const float vv = acc[mi][ni][j] + b0;
        const float vg = accg[mi][ni][j] + b1;
        outB[(size_t)rrow * N + col] = f2bf(vv / (1.f + expf(-vg)));
      }
    }
}

// ---------------------------------------------------------------------------
// contract (unfused): u[t,o] = bv[t,o] + u_in[t,o](=Dout) + sum_h hs[t,h]*cg[t,h*1024+o]
__global__ __launch_bounds__(256) void contract_kernel(
    const float* __restrict__ bv, const u16* __restrict__ cg,
    const float* __restrict__ hs, float* u) {
  const int t = blockIdx.x;
  const int tid = threadIdx.x;
  __shared__ float hsl[16];
  if (tid < 16) hsl[tid] = hs[(size_t)t * 16 + tid];
  __syncthreads();
  f32x4 acc = ((const f32x4*)(bv + (size_t)t * 1024))[tid];
  f32x4 dv = ((f32x4*)(u + (size_t)t * 1024))[tid];
  acc += dv;
  const u16* cgrow = cg + (size_t)t * 16384;
#pragma unroll
  for (int h = 0; h < 16; ++h) {
    float s = hsl[h];
    u16x4 cv = *(const u16x4*)(cgrow + h * 1024 + tid * 4);
    acc.x += s * bf2f(cv.x);
    acc.y += s * bf2f(cv.y);
    acc.z += s * bf2f(cv.z);
    acc.w += s * bf2f(cv.w);
  }
  ((f32x4*)(u + (size_t)t * 1024))[tid] = acc;
}

// ---------------------------------------------------------------------------
// Fused fallback (small ws): 512 threads / 8 waves (2m x 4n, wave-tile 64x32).
__global__ __launch_bounds__(512, 1) void fused_cgemm8(
    const u16* __restrict__ xbf, const u16* __restrict__ wc, const u16* __restrict__ wcg,
    const u16* __restrict__ wd, const float* __restrict__ bc, const float* __restrict__ bcg,
    const float* __restrict__ bd, const float* __restrict__ hs, const float* __restrict__ bv,
    float* __restrict__ u) {
  __shared__ u16 lds_a[2][128 * 32];
  __shared__ u16 lds_b[2][128 * 32];
  __shared__ u16 lds_g[2][128 * 32];
  __shared__ float hs_lds[128 * 16];

  const int tid = threadIdx.x;  // 0..511
  const int lane = tid & 63;
  const int w = tid >> 6;       // 0..7
  const int wm = w & 1, wn = w >> 1;  // 2 x 4
  const int row16 = lane & 15, kg = lane >> 4;

  const int lin = blockIdx.x;
  const int obase = (lin & 7) * 128;
  const int rowA = (lin >> 3) * 128;

  *(f32x4*)(hs_lds + tid * 4) = *(const f32x4*)(hs + (size_t)rowA * 16 + tid * 4);

  f32x4 accu[4][2] = {};
  f32x4 acc[4][2] = {};
  f32x4 accg[4][2] = {};

  auto stage = [&](int buf, int step) {
    const int h = step >> 5;
    const int k = (step & 31) * 32;
    const int r = tid >> 2;
    const int c = (tid & 3) << 3;
    async_copy16(&lds_a[buf][tid * 8], xbf + (size_t)(rowA + r) * 1024 + k + c);
    if (h < 16) {
      const size_t brow = (size_t)(h * 1024 + obase + r) * 1024 + k + c;
      async_copy16(&lds_b[buf][tid * 8], wc + brow);
      async_copy16(&lds_g[buf][tid * 8], wcg + brow);
    } else {
      async_copy16(&lds_b[buf][tid * 8], wd + (size_t)(obase + r) * 1024 + k + c);
    }
  };

  stage(0, 0);
  __syncthreads();

  for (int step = 0; step < 544; ++step) {
    const int buf = step & 1;
    const int h = step >> 5;
    if (step + 1 < 544) stage(buf ^ 1, step + 1);

    s16x8 af[4], bfr[2], gfr[2];
#pragma unroll
    for (int i = 0; i < 4; ++i)
      af[i] = *(const s16x8*)&lds_a[buf][(wm * 64 + i * 16 + row16) * 32 + kg * 8];
#pragma unroll
    for (int i = 0; i < 2; ++i)
      bfr[i] = *(const s16x8*)&lds_b[buf][(wn * 32 + i * 16 + row16) * 32 + kg * 8];
    if (h < 16) {
#pragma unroll
      for (int i = 0; i < 2; ++i)
        gfr[i] = *(const s16x8*)&lds_g[buf][(wn * 32 + i * 16 + row16) * 32 + kg * 8];
    }

#pragma unroll
    for (int mi = 0; mi < 4; ++mi)
#pragma unroll
      for (int ni = 0; ni < 2; ++ni)
        acc[mi][ni] = __builtin_amdgcn_mfma_f32_16x16x32_bf16(af[mi], bfr[ni], acc[mi][ni], 0, 0, 0);
    if (h < 16) {
#pragma unroll
      for (int mi = 0; mi < 4; ++mi)
#pragma unroll
        for (int ni = 0; ni < 2; ++ni)
          accg[mi][ni] =
              __builtin_amdgcn_mfma_f32_16x16x32_bf16(af[mi], gfr[ni], accg[mi][ni], 0, 0, 0);
    }

    if ((step & 31) == 31) {
      if (h < 16) {
#pragma unroll
        for (int ni = 0; ni < 2; ++ni) {
          const int ocol = obase + wn * 32 + ni * 16 + row16;
          const float b0 = bc[h * 1024 + ocol];
          const float b1 = bcg[h * 1024 + ocol];
#pragma unroll
          for (int mi = 0; mi < 4; ++mi)
#pragma unroll
            for (int j = 0; j < 4; ++j) {
              const int lrow = wm * 64 + mi * 16 + kg * 4 + j;
              const float hv = hs_lds[lrow * 16 + h];
              const float vv = acc[mi][ni][j] + b0;
              const float vg = accg[mi][ni][j] + b1;
              accu[mi][ni][j] += hv * vv / (1.f + expf(-vg));
              acc[mi][ni][j] = 0.f;
              accg[mi][ni][j] = 0.f;
            }
        }
      } else {
#pragma unroll
        for (int ni = 0; ni < 2; ++ni) {
          const int ocol = obase + wn * 32 + ni * 16 + row16;
          const float b0 = bd[ocol];
#pragma unroll
          for (int mi = 0; mi < 4; ++mi)
#pragma unroll
            for (int j = 0; j < 4; ++j)
              accu[mi][ni][j] += acc[mi][ni][j] + b0;
        }
      }
    }
    __syncthreads();
  }

#pragma unroll
  for (int mi = 0; mi < 4; ++mi)
#pragma unroll
    for (int ni = 0; ni < 2; ++ni) {
      const int ocol = obase + wn * 32 + ni * 16 + row16;
#pragma unroll
      for (int j = 0; j < 4; ++j) {
        const int grow = rowA + wm * 64 + mi * 16 + kg * 4 + j;
        const size_t idx = (size_t)grow * 1024 + ocol;
        u[idx] = accu[mi][ni][j] + bv[idx];
      }
    }
}

// ---------------------------------------------------------------------------
// Plain GEMM: wave tile 64x64, WM x WN waves. EPI: 0=+bias->f32; 2=gelu->bf16;
// 3=+bias+residF->f32. outF/residF may alias (same-thread r->w).
template <int WM, int WN, int EPI>
__global__ __launch_bounds__(WM * WN * 64, 2) void gemm_t(
    const u16* __restrict__ A, const u16* __restrict__ B0, const float* __restrict__ bias0,
    float* outF, u16* __restrict__ outB, const float* residF,
    int N, int K) {
  constexpr int BM = WM * 64, BN = WN * 64, BK = 32, T = WM * WN * 64;
  __shared__ u16 lds_a[BM * BK];
  __shared__ u16 lds_b[BN * BK];
  const int tid = threadIdx.x;
  const int lane = tid & 63;
  const int w = tid >> 6;
  const int wm = w % WM, wn = w / WM;
  const int row16 = lane & 15, kg = lane >> 4;
  const size_t rowA = (size_t)blockIdx.x * BM;
  const size_t rowB = (size_t)blockIdx.y * BN;
  f32x4 acc[4][4] = {};

  for (int k0 = 0; k0 < K; k0 += BK) {
#pragma unroll
    for (int s = 0; s < BM * 4 / T; ++s) {
      const int slot = s * T + tid;
      async_copy16(&lds_a[slot * 8], A + (rowA + (slot >> 2)) * K + k0 + ((slot & 3) << 3));
    }
#pragma unroll
    for (int s = 0; s < BN * 4 / T; ++s) {
      const int slot = s * T + tid;
      async_copy16(&lds_b[slot * 8], B0 + (rowB + (slot >> 2)) * K + k0 + ((slot & 3) << 3));
    }
    __syncthreads();

    s16x8 af[4], bfr[4];
#pragma unroll
    for (int i = 0; i < 4; ++i)
      af[i] = *(const s16x8*)&lds_a[(wm * 64 + i * 16 + row16) * BK + kg * 8];
#pragma unroll
    for (int i = 0; i < 4; ++i)
      bfr[i] = *(const s16x8*)&lds_b[(wn * 64 + i * 16 + row16) * BK + kg * 8];
#pragma unroll
    for (int mi = 0; mi < 4; ++mi)
#pragma unroll
      for (int ni = 0; ni < 4; ++ni)
        acc[mi][ni] = __builtin_amdgcn_mfma_f32_16x16x32_bf16(af[mi], bfr[ni], acc[mi][ni], 0, 0, 0);
    __syncthreads();
  }

  const int mbase = (int)rowA + wm * 64;
  const int nbase = (int)rowB + wn * 64;
#pragma unroll
  for (int mi = 0; mi < 4; ++mi) {
#pragma unroll
    for (int ni = 0; ni < 4; ++ni) {
      const int col = nbase + ni * 16 + row16;
      const float b0 = bias0[col];
#pragma unroll
      for (int j = 0; j < 4; ++j) {
        const int rrow = mbase + mi * 16 + kg * 4 + j;
        const size_t idx = (size_t)rrow * N + col;
        const float v = acc[mi][ni][j] + b0;
        if constexpr (EPI == 0) {
          outF[idx] = v;
        } else if constexpr (EPI == 2) {
          outB[idx] = f2bf(0.5f * v * (1.f + erff(v * 0.70710678118654752f)));
        } else {
          outF[idx] = v + residF[idx];
        }
      }
    }
  }
}

// ---------------------------------------------------------------------------
extern "C" void kernel_launch(void* const* d_in, const int* in_sizes, int n_in,
                              void* d_out, int out_size, void* d_ws, size_t ws_size,
                              hipStream_t stream) {
  const float* bv   = (const float*)d_in[0];
  const float* h0   = (const float*)d_in[1];
  const float* Aarr = (const float*)d_in[2];
  const float* Wb   = (const float*)d_in[3];
  const float* bb   = (const float*)d_in[4];
  const float* Wc   = (const float*)d_in[5];
  const float* bc   = (const float*)d_in[6];
  const float* Wd   = (const float*)d_in[7];
  const float* bd   = (const float*)d_in[8];
  const float* Wbg  = (const float*)d_in[9];
  const float* bbg  = (const float*)d_in[10];
  const float* Wcg  = (const float*)d_in[11];
  const float* bcg  = (const float*)d_in[12];
  const float* W1   = (const float*)d_in[13];
  const float* b1   = (const float*)d_in[14];
  const float* W2   = (const float*)d_in[15];
  const float* b2   = (const float*)d_in[16];
  const float* g1   = (const float*)d_in[17];
  const float* be1  = (const float*)d_in[18];
  const float* g2   = (const float*)d_in[19];
  const float* be2  = (const float*)d_in[20];

  float* out = (float*)d_out;
  float* out_lasth = out + (size_t)4096 * 1024;
  float* u_buf = out;  // u / Dout / y2-f32 live in d_out until FFN2 overwrites

  char* p = (char*)d_ws;
  auto take = [&](size_t bytes) -> char* {
    char* r = p;
    p += (bytes + 255) & ~(size_t)255;
    return r;
  };
  u16* wc_bf   = (u16*)take((size_t)16384 * 1024 * 2);  // 32 MB
  u16* wcg_bf  = (u16*)take((size_t)16384 * 1024 * 2);  // 32 MB
  u16* wd_bf   = (u16*)take((size_t)1024 * 1024 * 2);   //  2 MB
  u16* w1_bf   = (u16*)take((size_t)4096 * 1024 * 2);   //  8 MB
  u16* w2_bf   = (u16*)take((size_t)1024 * 4096 * 2);   //  8 MB
  u16* x_bf    = (u16*)take((size_t)4096 * 1024 * 2);   //  8 MB
  float* bg_tr = (float*)take((size_t)64 * 1024 * 4);   // .25 MB
  float* hs    = (float*)take((size_t)4096 * 16 * 4);   // .25 MB
  const size_t need_fused = (size_t)(p - (char*)d_ws);  // ~90.5 MB
  u16* cg_bf   = (u16*)take((size_t)4096 * 16384 * 2);  // +128 MB
  const size_t need_unfused = (size_t)(p - (char*)d_ws);  // ~218.5 MB
  if (ws_size < need_fused) return;
  const bool big_ws = (ws_size >= need_unfused);

  // aliases, live only after the C-GEMM stage is done with the weights
  u16* f1_bf = wc_bf;   // 32 MB
  u16* y2_bf = wcg_bf;  //  8 MB

  // 1. weight conversions
  cvt_f32_bf16<<<16384, 256, 0, stream>>>(Wc, wc_bf, 16384 * 1024 / 4);
  cvt_f32_bf16<<<16384, 256, 0, stream>>>(Wcg, wcg_bf, 16384 * 1024 / 4);
  cvt_f32_bf16<<<1024, 256, 0, stream>>>(Wd, wd_bf, 1024 * 1024 / 4);
  cvt_f32_bf16<<<4096, 256, 0, stream>>>(W1, w1_bf, 4096 * 1024 / 4);
  cvt_f32_bf16<<<4096, 256, 0, stream>>>(W2, w2_bf, 1024 * 4096 / 4);

  // 2. LN1 -> x_bf16
  ln_kernel<<<4096, 256, 0, stream>>>(bv, g1, be1, x_bf, nullptr);

  // 3. gated B projection (own f32 LN, exact) -> bg_tr
  bproj_kernel<<<4096, 256, 0, stream>>>(bv, g1, be1, Wb, bb, Wbg, bbg, bg_tr);

  // 4. scan -> hs, last_h
  scan_kernel<<<1, 64, 0, stream>>>(bg_tr, Aarr, h0, hs, out_lasth);

  if (big_ws) {
    // 5a. gated C GEMM -> cg_bf (4096 x 16384), 4096 blocks: full TLP
    gemm_gated<<<dim3(32, 128), 256, 0, stream>>>(x_bf, wc_bf, wcg_bf, bc, bcg, cg_bf,
                                                  16384, 1024);
    // 5b. Dout -> u_buf (d_out)
    gemm_t<2, 2, 0><<<dim3(32, 8), 256, 0, stream>>>(x_bf, wd_bf, bd, u_buf, nullptr, nullptr,
                                                     1024, 1024);
    // 5c. u = bv + Dout + sum_h hs*cg   (in-place on u_buf)
    contract_kernel<<<4096, 256, 0, stream>>>(bv, cg_bf, hs, u_buf);
  } else {
    // 5. fused fallback (8 waves/block)
    fused_cgemm8<<<256, 512, 0, stream>>>(x_bf, wc_bf, wcg_bf, wd_bf, bc, bcg, bd, hs, bv, u_buf);
  }

  // 6. LN2 -> y2_bf16 (+ f32 y2 in-place into u_buf)
  ln_kernel<<<4096, 256, 0, stream>>>(u_buf, g2, be2, y2_bf, u_buf);

  // 7. FFN1 exact-erf GELU -> f1_bf
  gemm_t<2, 2, 2><<<dim3(32, 32), 256, 0, stream>>>(y2_bf, w1_bf, b1, nullptr, f1_bf, nullptr,
                                                    4096, 1024);

  // 8. FFN2 + bias + residual(y2 f32) -> d_out
  gemm_t<1, 2, 3><<<dim3(64, 8), 128, 0, stream>>>(f1_bf, w2_bf, b2, out, nullptr, u_buf,
                                                   1024, 4096);
}